// Round 3
// baseline (236.341 us; speedup 1.0000x reference)
//
#include <hip/hip_runtime.h>

// ConditionalPreactivation: out = Z @ Wflat + bf @ bvec,
//   Z[b, k*512+i] = bf[b,k] * a[b,i],  a = lrelu(LN(x)),  bf = basis(c).
// GEMM with IN-REGISTER row-scaling of the A-fragment (bf applied as f16
// packed mul on the MFMA A operand), split-K over disjoint partial buffers,
// reduce folds the bf@bvec term.  B=4096, DIN=512, DOUT=512, DC=64, K=16.

#define LRELU(v) ((v) >= 0.f ? (v) : 0.01f * (v))

typedef _Float16 f16x8 __attribute__((ext_vector_type(8)));
typedef float f32x4 __attribute__((ext_vector_type(4)));

#define GL16(gp, lp) __builtin_amdgcn_global_load_lds(                      \
    (const __attribute__((address_space(1))) void*)(gp),                    \
    (__attribute__((address_space(3))) void*)(lp), 16, 0, 0)

// ---------------------------------------------------------------------------
// Fused prep: blocks [0,256)      basis functions -> bf f32   (longest chain first)
//             blocks [256,1280)   W f32 -> Wt f16 transposed [o][k*512+i]
//             blocks [1280,2304)  LayerNorm+lrelu -> a f16
// ---------------------------------------------------------------------------
__global__ __launch_bounds__(256) void prep_kernel(
    const float* __restrict__ x, const float* __restrict__ gam,
    const float* __restrict__ bet, _Float16* __restrict__ a,
    const float* __restrict__ c, const float* __restrict__ w1,
    const float* __restrict__ b1, const float* __restrict__ wr,
    const float* __restrict__ br, const float* __restrict__ w2,
    const float* __restrict__ b2, float* __restrict__ bfo,
    const float* __restrict__ W, _Float16* __restrict__ Wt)
{
    __shared__ __align__(16) char smem[36864];
    int tid = threadIdx.x;
    int blk = blockIdx.x;

    if (blk < 256) {
        // ---------------- basis functions -> bf ----------------
        float* c_l  = (float*)smem;             // 16*64  = 4 KB
        float* lr_l = (float*)(smem + 4096);    // 16*256 = 16 KB
        float* h_l  = (float*)(smem + 20480);   // 16*256 = 16 KB
        int b0 = blk * 16;

        for (int i = tid; i < 16 * 64; i += 256) c_l[i] = c[(size_t)b0 * 64 + i];
        __syncthreads();

        float b1s = b1[tid];
        float h1[16];
#pragma unroll
        for (int r = 0; r < 16; ++r) h1[r] = b1s;

        for (int j4 = 0; j4 < 16; ++j4) {
            float wa = w1[(j4 * 4 + 0) * 256 + tid];
            float wb = w1[(j4 * 4 + 1) * 256 + tid];
            float wc = w1[(j4 * 4 + 2) * 256 + tid];
            float wd = w1[(j4 * 4 + 3) * 256 + tid];
#pragma unroll
            for (int r = 0; r < 16; ++r) {
                float4 cv = *(const float4*)&c_l[r * 64 + j4 * 4];
                h1[r] += cv.x * wa + cv.y * wb + cv.z * wc + cv.w * wd;
            }
        }
#pragma unroll
        for (int r = 0; r < 16; ++r) lr_l[r * 256 + tid] = LRELU(h1[r]);
        __syncthreads();

        float brv = br[tid];
        float h2[16];
#pragma unroll
        for (int r = 0; r < 16; ++r) h2[r] = h1[r] + brv;

        for (int j4 = 0; j4 < 64; ++j4) {
            float wa = wr[(j4 * 4 + 0) * 256 + tid];
            float wb = wr[(j4 * 4 + 1) * 256 + tid];
            float wc = wr[(j4 * 4 + 2) * 256 + tid];
            float wd = wr[(j4 * 4 + 3) * 256 + tid];
#pragma unroll
            for (int r = 0; r < 16; ++r) {
                float4 lv = *(const float4*)&lr_l[r * 256 + j4 * 4];
                h2[r] += lv.x * wa + lv.y * wb + lv.z * wc + lv.w * wd;
            }
        }
#pragma unroll
        for (int r = 0; r < 16; ++r) h_l[r * 256 + tid] = LRELU(h2[r]);
        __syncthreads();

        int r = tid >> 4, k = tid & 15;
        float s = b2[k];
        for (int q4 = 0; q4 < 64; ++q4) {
            float4 hv = *(const float4*)&h_l[r * 256 + q4 * 4];
            s += hv.x * w2[(q4 * 4 + 0) * 16 + k];
            s += hv.y * w2[(q4 * 4 + 1) * 16 + k];
            s += hv.z * w2[(q4 * 4 + 2) * 16 + k];
            s += hv.w * w2[(q4 * 4 + 3) * 16 + k];
        }
        bfo[(size_t)(b0 + r) * 16 + k] = s;

    } else if (blk < 1280) {
        // ---------------- W transpose + f16 convert ----------------
        float* t = (float*)smem;  // 64*65*4 = 16.25 KB
        int bid = blk - 256;
        int k  = bid >> 6;
        int it = (bid >> 3) & 7;
        int ot = bid & 7;
        int i0 = it * 64, o0 = ot * 64;

        int rr = tid >> 4, c4 = (tid & 15) * 4;
#pragma unroll
        for (int p = 0; p < 4; ++p) {
            int r = p * 16 + rr;
            float4 v = *(const float4*)&W[((size_t)(k * 512 + i0 + r)) * 512 + o0 + c4];
            t[r * 65 + c4 + 0] = v.x;
            t[r * 65 + c4 + 1] = v.y;
            t[r * 65 + c4 + 2] = v.z;
            t[r * 65 + c4 + 3] = v.w;
        }
        __syncthreads();

        int ol = tid >> 2, c0 = (tid & 3) * 16;
        _Float16 hb[16] __attribute__((aligned(16)));
#pragma unroll
        for (int u = 0; u < 16; ++u) hb[u] = (_Float16)t[(c0 + u) * 65 + ol];
        _Float16* dst = &Wt[(size_t)(o0 + ol) * 8192 + k * 512 + i0 + c0];
        *(float4*)dst       = *(const float4*)&hb[0];
        *(float4*)(dst + 8) = *(const float4*)&hb[8];

    } else {
        // ---------------- LayerNorm + LeakyReLU ----------------
        int lane = tid & 63;
        int row  = (blk - 1280) * 4 + (tid >> 6);
        const float* xr = x + (size_t)row * 512 + lane * 8;
        float4 v0 = *(const float4*)xr;
        float4 v1 = *(const float4*)(xr + 4);

        float s = v0.x + v0.y + v0.z + v0.w + v1.x + v1.y + v1.z + v1.w;
#pragma unroll
        for (int m = 1; m < 64; m <<= 1) s += __shfl_xor(s, m);
        float mean = s * (1.f / 512.f);

        float d, s2 = 0.f;
        d = v0.x - mean; s2 += d * d;
        d = v0.y - mean; s2 += d * d;
        d = v0.z - mean; s2 += d * d;
        d = v0.w - mean; s2 += d * d;
        d = v1.x - mean; s2 += d * d;
        d = v1.y - mean; s2 += d * d;
        d = v1.z - mean; s2 += d * d;
        d = v1.w - mean; s2 += d * d;
#pragma unroll
        for (int m = 1; m < 64; m <<= 1) s2 += __shfl_xor(s2, m);
        float rstd = rsqrtf(s2 * (1.f / 512.f) + 1e-5f);

        float4 g0 = *(const float4*)&gam[lane * 8];
        float4 g1 = *(const float4*)&gam[lane * 8 + 4];
        float4 b0 = *(const float4*)&bet[lane * 8];
        float4 b1v = *(const float4*)&bet[lane * 8 + 4];

        _Float16 o8[8] __attribute__((aligned(16)));
        float y;
        y = (v0.x - mean) * rstd * g0.x + b0.x;  y = LRELU(y); o8[0] = (_Float16)y;
        y = (v0.y - mean) * rstd * g0.y + b0.y;  y = LRELU(y); o8[1] = (_Float16)y;
        y = (v0.z - mean) * rstd * g0.z + b0.z;  y = LRELU(y); o8[2] = (_Float16)y;
        y = (v0.w - mean) * rstd * g0.w + b0.w;  y = LRELU(y); o8[3] = (_Float16)y;
        y = (v1.x - mean) * rstd * g1.x + b1v.x; y = LRELU(y); o8[4] = (_Float16)y;
        y = (v1.y - mean) * rstd * g1.y + b1v.y; y = LRELU(y); o8[5] = (_Float16)y;
        y = (v1.z - mean) * rstd * g1.z + b1v.z; y = LRELU(y); o8[6] = (_Float16)y;
        y = (v1.w - mean) * rstd * g1.w + b1v.w; y = LRELU(y); o8[7] = (_Float16)y;

        *(float4*)&a[(size_t)row * 512 + lane * 8] = *(const float4*)o8;
    }
}

// ---------------------------------------------------------------------------
// Main GEMM: partial[split][b,o] = sum_{kt in split} ((bf[:,kt]*a) @ W[kt])[b,o]
// BM=BN=128, BK=64, 4 waves (2x2), 16x16x32 f16 MFMA.
// bf applied as f16 packed mul on the A-fragment (row-pure per lane: row=l16).
// A-tile staged ONCE per ks, shared across the kt-inner loop.
// ---------------------------------------------------------------------------
template <int NSPLIT>
__global__ __launch_bounds__(256, 3) void gemm_kernel(
    const _Float16* __restrict__ A,   // [4096][512]
    const _Float16* __restrict__ Wt,  // [512][8192]
    const float* __restrict__ bfg,    // [4096][16]
    float* __restrict__ pout)         // [NSPLIT][4096][512]
{
    constexpr int KTN = 16 / NSPLIT;
    constexpr int PER = 4 * NSPLIT;

    __shared__ _Float16 As[128 * 64];  // 16 KB
    __shared__ _Float16 Bs[128 * 64];  // 16 KB

    int tid = threadIdx.x;
    int bid = blockIdx.x;
    int m     = bid / PER;
    int cc    = bid % PER;
    int n     = cc / NSPLIT;
    int split = cc % NSPLIT;
    int bm0 = m * 128, n0 = n * 128, kt0 = split * KTN;

    int lane = tid & 63, wid = tid >> 6;
    int wm = wid >> 1, wn = wid & 1;
    int l16 = lane & 15, lg = lane >> 4;

    // per-lane A-row scales (A-fragment row = l16), converted once to f16
    _Float16 s16[KTN][4];
#pragma unroll
    for (int kt = 0; kt < KTN; ++kt)
#pragma unroll
        for (int mi = 0; mi < 4; ++mi)
            s16[kt][mi] =
                (_Float16)bfg[(size_t)(bm0 + wm * 64 + mi * 16 + l16) * 16 + kt0 + kt];

    const f32x4 z4 = {0.f, 0.f, 0.f, 0.f};
    f32x4 acc[4][4];
#pragma unroll
    for (int mi = 0; mi < 4; ++mi)
#pragma unroll
        for (int ni = 0; ni < 4; ++ni) acc[mi][ni] = z4;

    // staging addresses: idx = p*256+tid, rr = idx>>3, c8 = (idx&7)*8
    int rr0 = tid >> 3, c8 = (tid & 7) * 8;
    const _Float16* asrc0 = A + (size_t)(bm0 + rr0) * 512 + c8;
    const _Float16* bsrc0 = Wt + (size_t)(n0 + rr0) * 8192 + c8;
    char* asl = (char*)As + tid * 16;
    char* bsl = (char*)Bs + tid * 16;

#pragma unroll 1
    for (int ks = 0; ks < 8; ++ks) {
        int ig = ks * 64;
        f16x8 a8[2][4];
#pragma unroll
        for (int kt = 0; kt < KTN; ++kt) {
            if (kt == 0) {
#pragma unroll
                for (int p = 0; p < 4; ++p)
                    GL16(asrc0 + (size_t)(p * 32) * 512 + ig, asl + p * 4096);
            }
            const _Float16* bsrc = bsrc0 + (size_t)(kt0 + kt) * 512 + ig;
#pragma unroll
            for (int p = 0; p < 4; ++p)
                GL16(bsrc + (size_t)(p * 32) * 8192, bsl + p * 4096);
            __syncthreads();

            if (kt == 0) {
#pragma unroll
                for (int kk = 0; kk < 2; ++kk)
#pragma unroll
                    for (int mi = 0; mi < 4; ++mi)
                        a8[kk][mi] = *(const f16x8*)
                            &As[(wm * 64 + mi * 16 + l16) * 64 + kk * 32 + lg * 8];
            }
#pragma unroll
            for (int kk = 0; kk < 2; ++kk) {
                f16x8 b8[4];
#pragma unroll
                for (int ni = 0; ni < 4; ++ni)
                    b8[ni] = *(const f16x8*)
                        &Bs[(wn * 64 + ni * 16 + l16) * 64 + kk * 32 + lg * 8];
#pragma unroll
                for (int mi = 0; mi < 4; ++mi) {
                    f16x8 as = a8[kk][mi] * s16[kt][mi];
#pragma unroll
                    for (int ni = 0; ni < 4; ++ni)
                        acc[mi][ni] = __builtin_amdgcn_mfma_f32_16x16x32_f16(
                            as, b8[ni], acc[mi][ni], 0, 0, 0);
                }
            }
            __syncthreads();
        }
    }

    float* op = pout + (size_t)split * (4096 * 512);
#pragma unroll
    for (int mi = 0; mi < 4; ++mi)
#pragma unroll
        for (int j = 0; j < 4; ++j) {
            int grow = bm0 + wm * 64 + mi * 16 + lg * 4 + j;
#pragma unroll
            for (int ni = 0; ni < 4; ++ni) {
                int col = n0 + wn * 64 + ni * 16 + l16;
                op[(size_t)grow * 512 + col] = acc[mi][ni][j];
            }
        }
}

// ---------------------------------------------------------------------------
// out = sum over splits of partials + bf @ bvec.  One float4 per thread.
// ---------------------------------------------------------------------------
__global__ __launch_bounds__(256) void reduce_kernel(const float* __restrict__ p,
                                                     const float* __restrict__ bfg,
                                                     const float* __restrict__ bvec,
                                                     float* __restrict__ out,
                                                     int nsplit)
{
    size_t i = (size_t)blockIdx.x * 256 + threadIdx.x;  // float4 index
    const float4* p4 = (const float4*)p;
    float4 s = p4[i];
    for (int sp = 1; sp < nsplit; ++sp) {
        float4 v = p4[i + (size_t)sp * 524288];
        s.x += v.x; s.y += v.y; s.z += v.z; s.w += v.w;
    }
    int b = (int)(i >> 7);        // 128 float4 per row
    int c = (int)(i & 127);
    const float* bfr = bfg + (size_t)b * 16;
    const float4* bv4 = (const float4*)bvec;  // [16][128] float4
#pragma unroll
    for (int k = 0; k < 16; ++k) {
        float bk = bfr[k];
        float4 v = bv4[k * 128 + c];
        s.x += bk * v.x; s.y += bk * v.y; s.z += bk * v.z; s.w += bk * v.w;
    }
    ((float4*)out)[i] = s;
}

// ---------------------------------------------------------------------------
extern "C" void kernel_launch(void* const* d_in, const int* in_sizes, int n_in,
                              void* d_out, int out_size, void* d_ws, size_t ws_size,
                              hipStream_t stream)
{
    const float* x    = (const float*)d_in[0];
    const float* c    = (const float*)d_in[1];
    const float* gam  = (const float*)d_in[2];
    const float* bet  = (const float*)d_in[3];
    const float* w1   = (const float*)d_in[4];
    const float* b1   = (const float*)d_in[5];
    const float* wr   = (const float*)d_in[6];
    const float* br   = (const float*)d_in[7];
    const float* w2   = (const float*)d_in[8];
    const float* b2   = (const float*)d_in[9];
    const float* W    = (const float*)d_in[10];
    const float* bvec = (const float*)d_in[11];
    float* out = (float*)d_out;

    const size_t outBytes  = (size_t)4096 * 512 * 4;                  // 8 MB
    const size_t miscBytes = (8u << 20) + (4u << 20) + (256u << 10);  // Wt+a+bf

    int nsplit;
    if      (ws_size >= 4 * outBytes + miscBytes) nsplit = 4;
    else if (ws_size >= 2 * outBytes + miscBytes) nsplit = 2;
    else                                          nsplit = 1;

    char* ws = (char*)d_ws;
    size_t pbytes = (size_t)nsplit * outBytes;
    float*    part = (float*)ws;
    _Float16* Wt   = (_Float16*)(ws + pbytes);
    _Float16* af   = (_Float16*)(ws + pbytes + (8u << 20));
    float*    bf   = (float*)(ws + pbytes + (12u << 20));

    prep_kernel<<<dim3(2304), dim3(256), 0, stream>>>(
        x, gam, bet, af, c, w1, b1, wr, br, w2, b2, bf, W, Wt);

    if (nsplit == 4) {
        gemm_kernel<4><<<dim3(512), dim3(256), 0, stream>>>(af, Wt, bf, part);
    } else if (nsplit == 2) {
        gemm_kernel<2><<<dim3(256), dim3(256), 0, stream>>>(af, Wt, bf, part);
    } else {
        gemm_kernel<1><<<dim3(128), dim3(256), 0, stream>>>(af, Wt, bf, part);
    }
    reduce_kernel<<<dim3(2048), dim3(256), 0, stream>>>(part, bf, bvec, out, nsplit);
}

// Round 4
// 106.239 us; speedup vs baseline: 2.2246x; 2.2246x over previous
//
#include <hip/hip_runtime.h>

// ConditionalPreactivation: out = Z @ Wflat + bf @ bvec,
//   Z[b, k*512+i] = bf[b,k] * a[b,i],  a = lrelu(LN(x)),  bf = basis(c).
// Round-2-proven GEMM structure (kt outer, ks inner, acck epilogue, bvec
// folded per-kt), grid grown to 1024 (4 blocks/CU) via NSPLIT=8 (or BM=64
// fallback).  B=4096, DIN=512, DOUT=512, DC=64, K=16.

#define LRELU(v) ((v) >= 0.f ? (v) : 0.01f * (v))

typedef _Float16 f16x8 __attribute__((ext_vector_type(8)));
typedef float f32x4 __attribute__((ext_vector_type(4)));

#define GL16(gp, lp) __builtin_amdgcn_global_load_lds(                      \
    (const __attribute__((address_space(1))) void*)(gp),                    \
    (__attribute__((address_space(3))) void*)(lp), 16, 0, 0)

// ---------------------------------------------------------------------------
// Fused prep: blocks [0,256)      basis functions -> bf f32
//             blocks [256,1280)   W f32 -> Wt f16 transposed [o][k*512+i]
//             blocks [1280,2304)  LayerNorm+lrelu -> a f16
// ---------------------------------------------------------------------------
__global__ __launch_bounds__(256) void prep_kernel(
    const float* __restrict__ x, const float* __restrict__ gam,
    const float* __restrict__ bet, _Float16* __restrict__ a,
    const float* __restrict__ c, const float* __restrict__ w1,
    const float* __restrict__ b1, const float* __restrict__ wr,
    const float* __restrict__ br, const float* __restrict__ w2,
    const float* __restrict__ b2, float* __restrict__ bfo,
    const float* __restrict__ W, _Float16* __restrict__ Wt)
{
    __shared__ __align__(16) char smem[36864];
    int tid = threadIdx.x;
    int blk = blockIdx.x;

    if (blk < 256) {
        // ---------------- basis functions -> bf ----------------
        float* c_l  = (float*)smem;             // 16*64  = 4 KB
        float* lr_l = (float*)(smem + 4096);    // 16*256 = 16 KB
        float* h_l  = (float*)(smem + 20480);   // 16*256 = 16 KB
        int b0 = blk * 16;

        for (int i = tid; i < 16 * 64; i += 256) c_l[i] = c[(size_t)b0 * 64 + i];
        __syncthreads();

        float b1s = b1[tid];
        float h1[16];
#pragma unroll
        for (int r = 0; r < 16; ++r) h1[r] = b1s;

        for (int j4 = 0; j4 < 16; ++j4) {
            float wa = w1[(j4 * 4 + 0) * 256 + tid];
            float wb = w1[(j4 * 4 + 1) * 256 + tid];
            float wc = w1[(j4 * 4 + 2) * 256 + tid];
            float wd = w1[(j4 * 4 + 3) * 256 + tid];
#pragma unroll
            for (int r = 0; r < 16; ++r) {
                float4 cv = *(const float4*)&c_l[r * 64 + j4 * 4];
                h1[r] += cv.x * wa + cv.y * wb + cv.z * wc + cv.w * wd;
            }
        }
#pragma unroll
        for (int r = 0; r < 16; ++r) lr_l[r * 256 + tid] = LRELU(h1[r]);
        __syncthreads();

        float brv = br[tid];
        float h2[16];
#pragma unroll
        for (int r = 0; r < 16; ++r) h2[r] = h1[r] + brv;

        for (int j4 = 0; j4 < 64; ++j4) {
            float wa = wr[(j4 * 4 + 0) * 256 + tid];
            float wb = wr[(j4 * 4 + 1) * 256 + tid];
            float wc = wr[(j4 * 4 + 2) * 256 + tid];
            float wd = wr[(j4 * 4 + 3) * 256 + tid];
#pragma unroll
            for (int r = 0; r < 16; ++r) {
                float4 lv = *(const float4*)&lr_l[r * 256 + j4 * 4];
                h2[r] += lv.x * wa + lv.y * wb + lv.z * wc + lv.w * wd;
            }
        }
#pragma unroll
        for (int r = 0; r < 16; ++r) h_l[r * 256 + tid] = LRELU(h2[r]);
        __syncthreads();

        int r = tid >> 4, k = tid & 15;
        float s = b2[k];
        for (int q4 = 0; q4 < 64; ++q4) {
            float4 hv = *(const float4*)&h_l[r * 256 + q4 * 4];
            s += hv.x * w2[(q4 * 4 + 0) * 16 + k];
            s += hv.y * w2[(q4 * 4 + 1) * 16 + k];
            s += hv.z * w2[(q4 * 4 + 2) * 16 + k];
            s += hv.w * w2[(q4 * 4 + 3) * 16 + k];
        }
        bfo[(size_t)(b0 + r) * 16 + k] = s;

    } else if (blk < 1280) {
        // ---------------- W transpose + f16 convert ----------------
        float* t = (float*)smem;  // 64*65*4 = 16.25 KB
        int bid = blk - 256;
        int k  = bid >> 6;
        int it = (bid >> 3) & 7;
        int ot = bid & 7;
        int i0 = it * 64, o0 = ot * 64;

        int rr = tid >> 4, c4 = (tid & 15) * 4;
#pragma unroll
        for (int p = 0; p < 4; ++p) {
            int r = p * 16 + rr;
            float4 v = *(const float4*)&W[((size_t)(k * 512 + i0 + r)) * 512 + o0 + c4];
            t[r * 65 + c4 + 0] = v.x;
            t[r * 65 + c4 + 1] = v.y;
            t[r * 65 + c4 + 2] = v.z;
            t[r * 65 + c4 + 3] = v.w;
        }
        __syncthreads();

        int ol = tid >> 2, c0 = (tid & 3) * 16;
        _Float16 hb[16] __attribute__((aligned(16)));
#pragma unroll
        for (int u = 0; u < 16; ++u) hb[u] = (_Float16)t[(c0 + u) * 65 + ol];
        _Float16* dst = &Wt[(size_t)(o0 + ol) * 8192 + k * 512 + i0 + c0];
        *(float4*)dst       = *(const float4*)&hb[0];
        *(float4*)(dst + 8) = *(const float4*)&hb[8];

    } else {
        // ---------------- LayerNorm + LeakyReLU ----------------
        int lane = tid & 63;
        int row  = (blk - 1280) * 4 + (tid >> 6);
        const float* xr = x + (size_t)row * 512 + lane * 8;
        float4 v0 = *(const float4*)xr;
        float4 v1 = *(const float4*)(xr + 4);

        float s = v0.x + v0.y + v0.z + v0.w + v1.x + v1.y + v1.z + v1.w;
#pragma unroll
        for (int m = 1; m < 64; m <<= 1) s += __shfl_xor(s, m);
        float mean = s * (1.f / 512.f);

        float d, s2 = 0.f;
        d = v0.x - mean; s2 += d * d;
        d = v0.y - mean; s2 += d * d;
        d = v0.z - mean; s2 += d * d;
        d = v0.w - mean; s2 += d * d;
        d = v1.x - mean; s2 += d * d;
        d = v1.y - mean; s2 += d * d;
        d = v1.z - mean; s2 += d * d;
        d = v1.w - mean; s2 += d * d;
#pragma unroll
        for (int m = 1; m < 64; m <<= 1) s2 += __shfl_xor(s2, m);
        float rstd = rsqrtf(s2 * (1.f / 512.f) + 1e-5f);

        float4 g0 = *(const float4*)&gam[lane * 8];
        float4 g1 = *(const float4*)&gam[lane * 8 + 4];
        float4 b0 = *(const float4*)&bet[lane * 8];
        float4 b1v = *(const float4*)&bet[lane * 8 + 4];

        _Float16 o8[8] __attribute__((aligned(16)));
        float y;
        y = (v0.x - mean) * rstd * g0.x + b0.x;  y = LRELU(y); o8[0] = (_Float16)y;
        y = (v0.y - mean) * rstd * g0.y + b0.y;  y = LRELU(y); o8[1] = (_Float16)y;
        y = (v0.z - mean) * rstd * g0.z + b0.z;  y = LRELU(y); o8[2] = (_Float16)y;
        y = (v0.w - mean) * rstd * g0.w + b0.w;  y = LRELU(y); o8[3] = (_Float16)y;
        y = (v1.x - mean) * rstd * g1.x + b1v.x; y = LRELU(y); o8[4] = (_Float16)y;
        y = (v1.y - mean) * rstd * g1.y + b1v.y; y = LRELU(y); o8[5] = (_Float16)y;
        y = (v1.z - mean) * rstd * g1.z + b1v.z; y = LRELU(y); o8[6] = (_Float16)y;
        y = (v1.w - mean) * rstd * g1.w + b1v.w; y = LRELU(y); o8[7] = (_Float16)y;

        *(float4*)&a[(size_t)row * 512 + lane * 8] = *(const float4*)o8;
    }
}

// ---------------------------------------------------------------------------
// Main GEMM (round-2 structure): kt outer, ks inner, acck accumulator,
// bf scale + bvec fold in per-kt f32 epilogue.  BM x 128 tile, BK=64,
// 4 waves (2x2), 16x16x32 f16 MFMA, plain stores to split partial buffers.
// grid = (4096/BM) * 4 * NSPLIT;  bid = m*(4*NSPLIT) + n*NSPLIT + split
// ---------------------------------------------------------------------------
template <int NSPLIT, int BM>
__global__ __launch_bounds__(256, 2) void gemm_kernel(
    const _Float16* __restrict__ A,   // [4096][512]
    const _Float16* __restrict__ Wt,  // [512][8192]
    const float* __restrict__ bfg,    // [4096][16]
    const float* __restrict__ bvec,   // [16][512]
    float* __restrict__ pout)         // [NSPLIT][4096][512]
{
    constexpr int KTN = 16 / NSPLIT;   // kt-groups per split
    constexpr int PER = 4 * NSPLIT;
    constexpr int WM  = BM / 32;       // acc rows per wave (BM=128 -> 4)
    constexpr int APT = BM / 32;       // A-staging GL16s per thread

    __shared__ _Float16 As[BM * 64];
    __shared__ _Float16 Bs[128 * 64];
    __shared__ float bf_s[BM * KTN];

    int tid = threadIdx.x;
    int bid = blockIdx.x;
    int m     = bid / PER;
    int cc    = bid % PER;
    int n     = cc / NSPLIT;
    int split = cc % NSPLIT;
    int bm0 = m * BM, n0 = n * 128, kt0 = split * KTN;

    int lane = tid & 63, wid = tid >> 6;
    int wm = wid >> 1, wn = wid & 1;
    int l16 = lane & 15, lg = lane >> 4;

    for (int i = tid; i < BM * KTN; i += 256)
        bf_s[i] = bfg[(size_t)(bm0 + i / KTN) * 16 + kt0 + (i % KTN)];

    const f32x4 z4 = {0.f, 0.f, 0.f, 0.f};
    f32x4 acc[WM][4], acck[WM][4];
#pragma unroll
    for (int mi = 0; mi < WM; ++mi)
#pragma unroll
        for (int ni = 0; ni < 4; ++ni) { acc[mi][ni] = z4; acck[mi][ni] = z4; }

    for (int kt = 0; kt < KTN; ++kt) {
        int ktg = kt0 + kt;
        const _Float16* bsrc = Wt + (size_t)ktg * 512;
#pragma unroll 1
        for (int ks = 0; ks < 8; ++ks) {
            int ig = ks * 64;
#pragma unroll
            for (int p = 0; p < APT; ++p) {
                int idx = p * 256 + tid;
                int rr = idx >> 3, c8 = (idx & 7) * 8;
                GL16(A + (size_t)(bm0 + rr) * 512 + ig + c8, (char*)As + idx * 16);
            }
#pragma unroll
            for (int p = 0; p < 4; ++p) {
                int idx = p * 256 + tid;
                int rr = idx >> 3, c8 = (idx & 7) * 8;
                GL16(bsrc + (size_t)(n0 + rr) * 8192 + ig + c8, (char*)Bs + idx * 16);
            }
            __syncthreads();
#pragma unroll
            for (int kk = 0; kk < 2; ++kk) {
                f16x8 av[WM], bv_[4];
#pragma unroll
                for (int mi = 0; mi < WM; ++mi)
                    av[mi] = *(const f16x8*)
                        &As[(wm * (BM / 2) + mi * 16 + l16) * 64 + kk * 32 + lg * 8];
#pragma unroll
                for (int ni = 0; ni < 4; ++ni)
                    bv_[ni] = *(const f16x8*)
                        &Bs[(wn * 64 + ni * 16 + l16) * 64 + kk * 32 + lg * 8];
#pragma unroll
                for (int mi = 0; mi < WM; ++mi)
#pragma unroll
                    for (int ni = 0; ni < 4; ++ni)
                        acck[mi][ni] = __builtin_amdgcn_mfma_f32_16x16x32_f16(
                            av[mi], bv_[ni], acck[mi][ni], 0, 0, 0);
            }
            __syncthreads();
        }
        // acc += bf[row,ktg] * (acck + bvec[ktg,col]); reset acck
#pragma unroll
        for (int ni = 0; ni < 4; ++ni) {
            int col = n0 + wn * 64 + ni * 16 + l16;
            float bv = bvec[ktg * 512 + col];
#pragma unroll
            for (int mi = 0; mi < WM; ++mi) {
#pragma unroll
                for (int j = 0; j < 4; ++j) {
                    int rl = wm * (BM / 2) + mi * 16 + lg * 4 + j;
                    float s = bf_s[rl * KTN + kt];
                    acc[mi][ni][j] += s * (acck[mi][ni][j] + bv);
                    acck[mi][ni][j] = 0.f;
                }
            }
        }
    }

    float* op = pout + (size_t)split * (4096 * 512);
#pragma unroll
    for (int mi = 0; mi < WM; ++mi)
#pragma unroll
        for (int j = 0; j < 4; ++j) {
            int grow = bm0 + wm * (BM / 2) + mi * 16 + lg * 4 + j;
#pragma unroll
            for (int ni = 0; ni < 4; ++ni) {
                int col = n0 + wn * 64 + ni * 16 + l16;
                op[(size_t)grow * 512 + col] = acc[mi][ni][j];
            }
        }
}

// ---------------------------------------------------------------------------
// out = sum over splits of partials.  One float4 per thread.
// ---------------------------------------------------------------------------
__global__ __launch_bounds__(256) void reduce_kernel(const float* __restrict__ p,
                                                     float* __restrict__ out,
                                                     int nsplit)
{
    size_t i = (size_t)blockIdx.x * 256 + threadIdx.x;
    const float4* p4 = (const float4*)p;
    float4 s = p4[i];
    for (int sp = 1; sp < nsplit; ++sp) {
        float4 v = p4[i + (size_t)sp * 524288];
        s.x += v.x; s.y += v.y; s.z += v.z; s.w += v.w;
    }
    ((float4*)out)[i] = s;
}

// ---------------------------------------------------------------------------
extern "C" void kernel_launch(void* const* d_in, const int* in_sizes, int n_in,
                              void* d_out, int out_size, void* d_ws, size_t ws_size,
                              hipStream_t stream)
{
    const float* x    = (const float*)d_in[0];
    const float* c    = (const float*)d_in[1];
    const float* gam  = (const float*)d_in[2];
    const float* bet  = (const float*)d_in[3];
    const float* w1   = (const float*)d_in[4];
    const float* b1   = (const float*)d_in[5];
    const float* wr   = (const float*)d_in[6];
    const float* br   = (const float*)d_in[7];
    const float* w2   = (const float*)d_in[8];
    const float* b2   = (const float*)d_in[9];
    const float* W    = (const float*)d_in[10];
    const float* bvec = (const float*)d_in[11];
    float* out = (float*)d_out;

    const size_t outBytes  = (size_t)4096 * 512 * 4;                  // 8 MB
    const size_t miscBytes = (8u << 20) + (4u << 20) + (256u << 10);  // Wt+a+bf

    // nsplit=8 needs 76.25 MB of ws; nsplit=4 (44.25 MB) is known to fit.
    int nsplit = (ws_size >= 8 * outBytes + miscBytes) ? 8 : 4;

    char* ws = (char*)d_ws;
    size_t pbytes = (size_t)nsplit * outBytes;
    float*    part = (float*)ws;
    _Float16* Wt   = (_Float16*)(ws + pbytes);
    _Float16* af   = (_Float16*)(ws + pbytes + (8u << 20));
    float*    bf   = (float*)(ws + pbytes + (12u << 20));

    prep_kernel<<<dim3(2304), dim3(256), 0, stream>>>(
        x, gam, bet, af, c, w1, b1, wr, br, w2, b2, bf, W, Wt);

    if (nsplit == 8) {
        // 32 m-tiles * 4 n-tiles * 8 splits = 1024 blocks (4 per CU)
        gemm_kernel<8, 128><<<dim3(1024), dim3(256), 0, stream>>>(af, Wt, bf, bvec, part);
    } else {
        // 64 m-tiles * 4 n-tiles * 4 splits = 1024 blocks (4 per CU)
        gemm_kernel<4, 64><<<dim3(1024), dim3(256), 0, stream>>>(af, Wt, bf, bvec, part);
    }
    reduce_kernel<<<dim3(2048), dim3(256), 0, stream>>>(part, out, nsplit);
}